// Round 1
// baseline (1626.598 us; speedup 1.0000x reference)
//
#include <hip/hip_runtime.h>
#include <hip/hip_bf16.h>
#include <math.h>

// Problem constants
#define DIM   1024
#define NHEAD 16
#define SLEN  2048
#define BATCH 2
#define NROWS (BATCH*SLEN)   // 4096
#define QKV_N 3072

__device__ __forceinline__ float bfr(float x) {
  // float -> bf16 (RNE) -> float
  return __bfloat162float(__float2bfloat16(x));
}

// ---------------- rope tables (match numpy f32 semantics) ----------------
__global__ void __launch_bounds__(256) k_rope_tab(float* __restrict__ cosT,
                                                  float* __restrict__ sinT) {
  int idx = blockIdx.x * 256 + threadIdx.x;        // 2048*32 = 65536
  int s = idx >> 5, j = idx & 31;
  double inv  = 1.0 / pow(10000.0, (double)(2 * j) / 64.0);
  double ramp = ((double)(2 * j) / 64.0 - 0.25) / 0.75;
  ramp = ramp < 0.0 ? 0.0 : (ramp > 1.0 ? 1.0 : ramp);
  inv /= (ramp * 3.0 + 1.0);                       // yarn: 1/scale - 1 = 3
  float freq = (float)s * (float)inv;              // f32 product like reference
  cosT[idx] = (float)cos((double)freq);
  sinT[idx] = (float)sin((double)freq);
}

// ---------------- ternary quantization (bf16-faithful) ----------------
// one 64-lane wave per group of 64 consecutive elements
__global__ void __launch_bounds__(256) k_ternary(const float* __restrict__ in,
                                                 float* __restrict__ out) {
  int idx = blockIdx.x * 256 + threadIdx.x;
  float wb = bfr(in[idx]);
  float a = fabsf(wb);
  #pragma unroll
  for (int off = 32; off >= 1; off >>= 1) a += __shfl_xor(a, off);
  float scale = bfr(a * (1.0f / 64.0f));           // bf16 mean (f32 accum)
  scale = fmaxf(scale, 1e-8f);
  float ratio = bfr(wb / scale);
  float q = rintf(ratio);                          // half-to-even like jnp.round
  q = fminf(1.0f, fmaxf(-1.0f, q));
  float deq = bfr(q * scale);
  // forward value is bf16(wb + bf16(deq - wb))
  float d = bfr(deq - wb);
  out[idx] = bfr(wb + d);
}

// ---------------- fp32 GEMM  C[M,N] = A[M,K] * B[N,K]^T ----------------
// BM=BN=128, BK=16, 256 threads, 8x8 microtile
__global__ void __launch_bounds__(256) k_gemm_nt(const float* __restrict__ A,
                                                 const float* __restrict__ B,
                                                 float* __restrict__ C,
                                                 int M, int N, int K) {
  __shared__ float As[16][132];
  __shared__ float Bs[16][132];
  const int t = threadIdx.x;
  const int bm = blockIdx.y * 128, bn = blockIdx.x * 128;
  const int tx = t & 15, ty = t >> 4;
  float acc[8][8] = {};
  for (int k0 = 0; k0 < K; k0 += 16) {
    #pragma unroll
    for (int l = 0; l < 2; ++l) {
      int f = l * 1024 + t * 4;
      int r = f >> 4, c = f & 15;
      float4 va = *(const float4*)(A + (size_t)(bm + r) * K + k0 + c);
      As[c + 0][r] = va.x; As[c + 1][r] = va.y; As[c + 2][r] = va.z; As[c + 3][r] = va.w;
      float4 vb = *(const float4*)(B + (size_t)(bn + r) * K + k0 + c);
      Bs[c + 0][r] = vb.x; Bs[c + 1][r] = vb.y; Bs[c + 2][r] = vb.z; Bs[c + 3][r] = vb.w;
    }
    __syncthreads();
    #pragma unroll
    for (int kk = 0; kk < 16; ++kk) {
      float4 a0 = *(const float4*)&As[kk][ty * 8];
      float4 a1 = *(const float4*)&As[kk][ty * 8 + 4];
      float4 b0 = *(const float4*)&Bs[kk][tx * 8];
      float4 b1 = *(const float4*)&Bs[kk][tx * 8 + 4];
      float av[8] = {a0.x, a0.y, a0.z, a0.w, a1.x, a1.y, a1.z, a1.w};
      float bv[8] = {b0.x, b0.y, b0.z, b0.w, b1.x, b1.y, b1.z, b1.w};
      #pragma unroll
      for (int i = 0; i < 8; ++i)
        #pragma unroll
        for (int j = 0; j < 8; ++j)
          acc[i][j] = fmaf(av[i], bv[j], acc[i][j]);
    }
    __syncthreads();
  }
  #pragma unroll
  for (int i = 0; i < 8; ++i) {
    float4 o0 = {acc[i][0], acc[i][1], acc[i][2], acc[i][3]};
    float4 o1 = {acc[i][4], acc[i][5], acc[i][6], acc[i][7]};
    *(float4*)(C + (size_t)(bm + ty * 8 + i) * N + bn + tx * 8) = o0;
    *(float4*)(C + (size_t)(bm + ty * 8 + i) * N + bn + tx * 8 + 4) = o1;
  }
}

// ---------------- rmsnorm + rope + q_gain ----------------
// one wave per (row, {q-head or k-head}); lane = dim 0..63
__global__ void __launch_bounds__(256) k_normrope(const float* __restrict__ QKV,
    const float* __restrict__ cosT, const float* __restrict__ sinT,
    const float* __restrict__ q_gain, float* __restrict__ QP, float* __restrict__ KP) {
  int gid = blockIdx.x * 256 + threadIdx.x;
  int lane = gid & 63;
  int w = gid >> 6;            // wave id 0..131071
  int r = w >> 5;              // row 0..4095
  int u = w & 31;
  int isk = u >> 4, h = u & 15;
  float x = QKV[(size_t)r * 3072 + isk * 1024 + h * 64 + lane];
  float ss = x * x;
  #pragma unroll
  for (int off = 32; off >= 1; off >>= 1) ss += __shfl_xor(ss, off);
  float xn = x * rsqrtf(ss * (1.0f / 64.0f) + 1e-5f);
  int s = r & (SLEN - 1);
  int j = lane & 31;
  float c = cosT[s * 32 + j], sn = sinT[s * 32 + j];
  float other = __shfl_xor(xn, 32);
  // lane<32: x1*c + x2*s ; lane>=32: -x1*s + x2*c
  float o = (lane < 32) ? fmaf(xn, c, other * sn) : fmaf(xn, c, -other * sn);
  if (!isk) o *= q_gain[h];
  float* dst = isk ? KP : QP;
  dst[(size_t)r * 1024 + h * 64 + lane] = o;
}

// ---------------- fp32 flash attention, d=32, 64-q tile, 64-k chunks ----------
__global__ void __launch_bounds__(256) k_attn(const float* __restrict__ QP,
    const float* __restrict__ KP, const float* __restrict__ QKV,
    float* __restrict__ OH) {
  __shared__ float Qs[32][64];     // [d][qr]
  __shared__ float Ks[32][68];     // [d][kc]
  __shared__ float Vs[64][34];     // [kc][d]
  __shared__ float Sc[64][68];     // [qr][kc]
  __shared__ float Mrow[64], Lrow[64], Arow[64];
  const int qt = blockIdx.x, hh = blockIdx.y, b = blockIdx.z;
  const int t = threadIdx.x;
  const int h = hh & 15, half = hh >> 4;
  const int q0 = qt * 64;
  const int qkcol = h * 64 + half * 32;
  const int vcol = 2048 + qkcol;
  const int tx = t & 15, ty = t >> 4;

  #pragma unroll
  for (int l = 0; l < 2; ++l) {
    int f = l * 1024 + t * 4;
    int qr = f >> 5, d = f & 31;
    float4 v = *(const float4*)(QP + (size_t)(b * SLEN + q0 + qr) * 1024 + qkcol + d);
    Qs[d + 0][qr] = v.x; Qs[d + 1][qr] = v.y; Qs[d + 2][qr] = v.z; Qs[d + 3][qr] = v.w;
  }
  if (t < 64) { Mrow[t] = -INFINITY; Lrow[t] = 0.0f; }
  float acc[4][2] = {};
  const float sscale = 0.17677669529663687f;   // 1/sqrt(32)

  for (int cc = 0; cc <= qt; ++cc) {
    const int k0 = cc * 64;
    __syncthreads();                            // protect Sc/Vs/Ks of prev iter (and Qs/Mrow init)
    #pragma unroll
    for (int l = 0; l < 2; ++l) {
      int f = l * 1024 + t * 4;
      int kr = f >> 5, d = f & 31;
      float4 kv = *(const float4*)(KP + (size_t)(b * SLEN + k0 + kr) * 1024 + qkcol + d);
      Ks[d + 0][kr] = kv.x; Ks[d + 1][kr] = kv.y; Ks[d + 2][kr] = kv.z; Ks[d + 3][kr] = kv.w;
      float4 vv = *(const float4*)(QKV + (size_t)(b * SLEN + k0 + kr) * 3072 + vcol + d);
      Vs[kr][d + 0] = vv.x; Vs[kr][d + 1] = vv.y; Vs[kr][d + 2] = vv.z; Vs[kr][d + 3] = vv.w;
    }
    __syncthreads();
    // scores: 4x4 per thread
    {
      float sacc[4][4] = {};
      #pragma unroll
      for (int d = 0; d < 32; ++d) {
        float4 qa = *(const float4*)&Qs[d][ty * 4];
        float4 kb = *(const float4*)&Ks[d][tx * 4];
        float a_[4] = {qa.x, qa.y, qa.z, qa.w};
        float b_[4] = {kb.x, kb.y, kb.z, kb.w};
        #pragma unroll
        for (int i = 0; i < 4; ++i)
          #pragma unroll
          for (int j = 0; j < 4; ++j)
            sacc[i][j] = fmaf(a_[i], b_[j], sacc[i][j]);
      }
      #pragma unroll
      for (int i = 0; i < 4; ++i)
        #pragma unroll
        for (int j = 0; j < 4; ++j) {
          int kg = k0 + tx * 4 + j, qg = q0 + ty * 4 + i;
          Sc[ty * 4 + i][tx * 4 + j] = (kg <= qg) ? sacc[i][j] * sscale : -INFINITY;
        }
    }
    __syncthreads();
    // online softmax: 4 lanes per row
    {
      int row = t >> 2, part = t & 3;
      float mloc = -INFINITY;
      #pragma unroll
      for (int kc = 0; kc < 16; ++kc) mloc = fmaxf(mloc, Sc[row][part * 16 + kc]);
      mloc = fmaxf(mloc, __shfl_xor(mloc, 1));
      mloc = fmaxf(mloc, __shfl_xor(mloc, 2));
      float mold = Mrow[row];
      float mnew = fmaxf(mold, mloc);
      float lpart = 0.0f;
      #pragma unroll
      for (int kc = 0; kc < 16; ++kc) {
        float p = expf(Sc[row][part * 16 + kc] - mnew);
        Sc[row][part * 16 + kc] = p;
        lpart += p;
      }
      lpart += __shfl_xor(lpart, 1);
      lpart += __shfl_xor(lpart, 2);
      if (part == 0) {
        Arow[row] = expf(mold - mnew);
        Mrow[row] = mnew;
        Lrow[row] = Lrow[row] * Arow[row] + lpart;
      }
    }
    __syncthreads();
    // PV: thread tile 4 rows x 2 cols
    {
      #pragma unroll
      for (int i = 0; i < 4; ++i) {
        float al = Arow[ty * 4 + i];
        acc[i][0] *= al; acc[i][1] *= al;
      }
      for (int kc = 0; kc < 64; kc += 4) {
        float s_[4][4];
        #pragma unroll
        for (int i = 0; i < 4; ++i) {
          float4 tmp = *(const float4*)&Sc[ty * 4 + i][kc];
          s_[i][0] = tmp.x; s_[i][1] = tmp.y; s_[i][2] = tmp.z; s_[i][3] = tmp.w;
        }
        #pragma unroll
        for (int q = 0; q < 4; ++q) {
          float2 vv = *(const float2*)&Vs[kc + q][tx * 2];
          #pragma unroll
          for (int i = 0; i < 4; ++i) {
            acc[i][0] = fmaf(s_[i][q], vv.x, acc[i][0]);
            acc[i][1] = fmaf(s_[i][q], vv.y, acc[i][1]);
          }
        }
      }
    }
  }
  #pragma unroll
  for (int i = 0; i < 4; ++i) {
    float inv = 1.0f / Lrow[ty * 4 + i];
    float2 o = {acc[i][0] * inv, acc[i][1] * inv};
    *(float2*)(OH + ((size_t)(b * SLEN + q0 + ty * 4 + i) * 32 + hh) * 32 + tx * 2) = o;
  }
}

// ---------------- differential combine: y = [y1 - lam*y2, y1 + lam*y2] -------
__global__ void __launch_bounds__(256) k_combine(const float* __restrict__ OH,
    const float* __restrict__ dl, float* __restrict__ Y) {
  int idx = blockIdx.x * 256 + threadIdx.x;   // 4096*16*32
  int d = idx & 31;
  int h = (idx >> 5) & 15;
  int r = idx >> 9;
  float y1 = OH[((size_t)r * 32 + h) * 32 + d];
  float y2 = OH[((size_t)r * 32 + h + 16) * 32 + d];
  float lam = dl[h];
  Y[(size_t)r * 1024 + h * 64 + d]      = y1 - lam * y2;
  Y[(size_t)r * 1024 + h * 64 + 32 + d] = y1 + lam * y2;
}

// ---------------- prototype projection -> A1T[f][o], A2T[f][o] ----------------
__global__ void __launch_bounds__(256) k_protproj(const float* __restrict__ PT,
    const float* __restrict__ features, const float* __restrict__ thp,
    const float* __restrict__ alp, const float* __restrict__ bep,
    float* __restrict__ A1T, float* __restrict__ A2T) {
  int o = blockIdx.x, t = threadIdx.x;
  int f = t >> 4, seg = t & 15;
  const float* pr = PT + (size_t)o * 1024 + seg * 64;
  const float* fr = features + (size_t)f * 1024 + seg * 64;
  float acc = 0.0f;
  #pragma unroll
  for (int i = 0; i < 64; i += 4) {
    float4 a = *(const float4*)(pr + i);
    float4 bq = *(const float4*)(fr + i);
    acc = fmaf(a.x, bq.x, acc); acc = fmaf(a.y, bq.y, acc);
    acc = fmaf(a.z, bq.z, acc); acc = fmaf(a.w, bq.w, acc);
  }
  acc += __shfl_xor(acc, 1); acc += __shfl_xor(acc, 2);
  acc += __shfl_xor(acc, 4); acc += __shfl_xor(acc, 8);
  if (seg == 0) {
    float pf = acc;
    float ps = 1.0f / (1.0f + expf(-5.0f * pf));
    float pa = pf * ps;
    A1T[f * 1024 + o] = fabsf(*thp) * pa - fabsf(*alp) * (1.0f - ps);
    A2T[f * 1024 + o] = -fabsf(*bep) * pa;
  }
}

// ---------------- x features: x_a and (1-x_s) ----------------
__global__ void __launch_bounds__(256) k_xfeat(const float* __restrict__ Y,
    const float* __restrict__ features, float* __restrict__ XA, float* __restrict__ XS1) {
  int r = blockIdx.x, t = threadIdx.x;
  int f = t >> 4, seg = t & 15;
  const float* yr = Y + (size_t)r * 1024 + seg * 64;
  const float* fr = features + (size_t)f * 1024 + seg * 64;
  float acc = 0.0f;
  #pragma unroll
  for (int i = 0; i < 64; i += 4) {
    float4 a = *(const float4*)(yr + i);
    float4 bq = *(const float4*)(fr + i);
    acc = fmaf(a.x, bq.x, acc); acc = fmaf(a.y, bq.y, acc);
    acc = fmaf(a.z, bq.z, acc); acc = fmaf(a.w, bq.w, acc);
  }
  acc += __shfl_xor(acc, 1); acc += __shfl_xor(acc, 2);
  acc += __shfl_xor(acc, 4); acc += __shfl_xor(acc, 8);
  if (seg == 0) {
    float xf = acc;
    float xs = 1.0f / (1.0f + expf(-5.0f * xf));
    XA[r * 16 + f] = xf * xs;
    XS1[r * 16 + f] = 1.0f - xs;
  }
}

// ---------------- final: out = XA @ A1T + XS1 @ A2T ----------------
__global__ void __launch_bounds__(256) k_final(const float* __restrict__ XA,
    const float* __restrict__ XS1, const float* __restrict__ A1T,
    const float* __restrict__ A2T, float* __restrict__ out) {
  int r = blockIdx.x, t = threadIdx.x;
  float xa[16], x1[16];
  #pragma unroll
  for (int f4 = 0; f4 < 16; f4 += 4) {
    float4 a = *(const float4*)(XA + r * 16 + f4);
    float4 b = *(const float4*)(XS1 + r * 16 + f4);
    xa[f4] = a.x; xa[f4 + 1] = a.y; xa[f4 + 2] = a.z; xa[f4 + 3] = a.w;
    x1[f4] = b.x; x1[f4 + 1] = b.y; x1[f4 + 2] = b.z; x1[f4 + 3] = b.w;
  }
  float4 acc = {0.f, 0.f, 0.f, 0.f};
  #pragma unroll
  for (int f = 0; f < 16; ++f) {
    float4 a1 = *(const float4*)(A1T + f * 1024 + t * 4);
    float4 a2 = *(const float4*)(A2T + f * 1024 + t * 4);
    acc.x = fmaf(xa[f], a1.x, fmaf(x1[f], a2.x, acc.x));
    acc.y = fmaf(xa[f], a1.y, fmaf(x1[f], a2.y, acc.y));
    acc.z = fmaf(xa[f], a1.z, fmaf(x1[f], a2.z, acc.z));
    acc.w = fmaf(xa[f], a1.w, fmaf(x1[f], a2.w, acc.w));
  }
  *(float4*)(out + (size_t)r * 1024 + t * 4) = acc;
}

extern "C" void kernel_launch(void* const* d_in, const int* in_sizes, int n_in,
                              void* d_out, int out_size, void* d_ws, size_t ws_size,
                              hipStream_t stream) {
  const float* x      = (const float*)d_in[0];
  const float* w_qkv  = (const float*)d_in[1];
  const float* feats  = (const float*)d_in[2];
  const float* protos = (const float*)d_in[3];
  const float* theta  = (const float*)d_in[4];
  const float* alpha  = (const float*)d_in[5];
  const float* beta   = (const float*)d_in[6];
  const float* q_gain = (const float*)d_in[7];
  const float* dlam   = (const float*)d_in[8];
  float* out = (float*)d_out;
  float* ws  = (float*)d_ws;

  // workspace layout (floats); total 33,849,344 floats = 135.4 MB
  float* W_T = ws;                    // 3,145,728
  float* QKV = W_T + 3145728;         // 12,582,912
  float* QP  = QKV + 12582912;        // 4,194,304
  float* KP  = QP  + 4194304;         // 4,194,304
  float* OH  = KP  + 4194304;         // 4,194,304
  float* Y   = OH  + 4194304;         // 4,194,304
  float* COS = Y   + 4194304;         // 65,536
  float* SIN = COS + 65536;           // 65,536
  float* PT  = SIN + 65536;           // 1,048,576
  float* A1T = PT  + 1048576;         // 16,384
  float* A2T = A1T + 16384;           // 16,384
  float* XA  = A2T + 16384;           // 65,536
  float* XS1 = XA  + 65536;           // 65,536

  k_rope_tab<<<256, 256, 0, stream>>>(COS, SIN);
  k_ternary<<<12288, 256, 0, stream>>>(w_qkv, W_T);     // 3,145,728 elems
  k_ternary<<<4096, 256, 0, stream>>>(protos, PT);      // 1,048,576 elems
  dim3 gg(QKV_N / 128, NROWS / 128);
  k_gemm_nt<<<gg, 256, 0, stream>>>(x, W_T, QKV, NROWS, QKV_N, DIM);
  k_normrope<<<32768, 256, 0, stream>>>(QKV, COS, SIN, q_gain, QP, KP);
  dim3 ga(SLEN / 64, 32, BATCH);
  k_attn<<<ga, 256, 0, stream>>>(QP, KP, QKV, OH);
  k_combine<<<8192, 256, 0, stream>>>(OH, dlam, Y);
  k_protproj<<<1024, 256, 0, stream>>>(PT, feats, theta, alpha, beta, A1T, A2T);
  k_xfeat<<<4096, 256, 0, stream>>>(Y, feats, XA, XS1);
  k_final<<<4096, 256, 0, stream>>>(XA, XS1, A1T, A2T, out);
}

// Round 2
// 976.900 us; speedup vs baseline: 1.6651x; 1.6651x over previous
//
#include <hip/hip_runtime.h>
#include <hip/hip_bf16.h>
#include <math.h>

// Problem constants
#define DIM   1024
#define NHEAD 16
#define SLEN  2048
#define BATCH 2
#define NROWS (BATCH*SLEN)   // 4096
#define QKV_N 3072

__device__ __forceinline__ float bfr(float x) {
  // float -> bf16 (RNE) -> float
  return __bfloat162float(__float2bfloat16(x));
}

// ---------------- rope tables (match numpy f32 semantics) ----------------
__global__ void __launch_bounds__(256) k_rope_tab(float* __restrict__ cosT,
                                                  float* __restrict__ sinT) {
  int idx = blockIdx.x * 256 + threadIdx.x;        // 2048*32 = 65536
  int s = idx >> 5, j = idx & 31;
  double inv  = 1.0 / pow(10000.0, (double)(2 * j) / 64.0);
  double ramp = ((double)(2 * j) / 64.0 - 0.25) / 0.75;
  ramp = ramp < 0.0 ? 0.0 : (ramp > 1.0 ? 1.0 : ramp);
  inv /= (ramp * 3.0 + 1.0);                       // yarn: 1/scale - 1 = 3
  float freq = (float)s * (float)inv;              // f32 product like reference
  cosT[idx] = (float)cos((double)freq);
  sinT[idx] = (float)sin((double)freq);
}

// ---------------- ternary quantization (bf16-faithful) ----------------
// one 64-lane wave per group of 64 consecutive elements
__global__ void __launch_bounds__(256) k_ternary(const float* __restrict__ in,
                                                 float* __restrict__ out) {
  int idx = blockIdx.x * 256 + threadIdx.x;
  float wb = bfr(in[idx]);
  float a = fabsf(wb);
  #pragma unroll
  for (int off = 32; off >= 1; off >>= 1) a += __shfl_xor(a, off);
  float scale = bfr(a * (1.0f / 64.0f));           // bf16 mean (f32 accum)
  scale = fmaxf(scale, 1e-8f);
  float ratio = bfr(wb / scale);
  float q = rintf(ratio);                          // half-to-even like jnp.round
  q = fminf(1.0f, fmaxf(-1.0f, q));
  float deq = bfr(q * scale);
  // forward value is bf16(wb + bf16(deq - wb))
  float d = bfr(deq - wb);
  out[idx] = bfr(wb + d);
}

// ---------------- fp32 GEMM  C[M,N] = A[M,K] * B[N,K]^T ----------------
// BM=BN=128, BK=16, 256 threads, 8x8 microtile
__global__ void __launch_bounds__(256) k_gemm_nt(const float* __restrict__ A,
                                                 const float* __restrict__ B,
                                                 float* __restrict__ C,
                                                 int M, int N, int K) {
  __shared__ float As[16][132];
  __shared__ float Bs[16][132];
  const int t = threadIdx.x;
  const int bm = blockIdx.y * 128, bn = blockIdx.x * 128;
  const int tx = t & 15, ty = t >> 4;
  float acc[8][8] = {};
  for (int k0 = 0; k0 < K; k0 += 16) {
    #pragma unroll
    for (int l = 0; l < 2; ++l) {
      int f = l * 1024 + t * 4;
      int r = f >> 4, c = f & 15;
      float4 va = *(const float4*)(A + (size_t)(bm + r) * K + k0 + c);
      As[c + 0][r] = va.x; As[c + 1][r] = va.y; As[c + 2][r] = va.z; As[c + 3][r] = va.w;
      float4 vb = *(const float4*)(B + (size_t)(bn + r) * K + k0 + c);
      Bs[c + 0][r] = vb.x; Bs[c + 1][r] = vb.y; Bs[c + 2][r] = vb.z; Bs[c + 3][r] = vb.w;
    }
    __syncthreads();
    #pragma unroll
    for (int kk = 0; kk < 16; ++kk) {
      float4 a0 = *(const float4*)&As[kk][ty * 8];
      float4 a1 = *(const float4*)&As[kk][ty * 8 + 4];
      float4 b0 = *(const float4*)&Bs[kk][tx * 8];
      float4 b1 = *(const float4*)&Bs[kk][tx * 8 + 4];
      float av[8] = {a0.x, a0.y, a0.z, a0.w, a1.x, a1.y, a1.z, a1.w};
      float bv[8] = {b0.x, b0.y, b0.z, b0.w, b1.x, b1.y, b1.z, b1.w};
      #pragma unroll
      for (int i = 0; i < 8; ++i)
        #pragma unroll
        for (int j = 0; j < 8; ++j)
          acc[i][j] = fmaf(av[i], bv[j], acc[i][j]);
    }
    __syncthreads();
  }
  #pragma unroll
  for (int i = 0; i < 8; ++i) {
    float4 o0 = {acc[i][0], acc[i][1], acc[i][2], acc[i][3]};
    float4 o1 = {acc[i][4], acc[i][5], acc[i][6], acc[i][7]};
    *(float4*)(C + (size_t)(bm + ty * 8 + i) * N + bn + tx * 8) = o0;
    *(float4*)(C + (size_t)(bm + ty * 8 + i) * N + bn + tx * 8 + 4) = o1;
  }
}

// ---------------- rmsnorm + rope + q_gain ----------------
// one wave per (row, {q-head or k-head}); lane = dim 0..63
__global__ void __launch_bounds__(256) k_normrope(const float* __restrict__ QKV,
    const float* __restrict__ cosT, const float* __restrict__ sinT,
    const float* __restrict__ q_gain, float* __restrict__ QP, float* __restrict__ KP) {
  int gid = blockIdx.x * 256 + threadIdx.x;
  int lane = gid & 63;
  int w = gid >> 6;            // wave id 0..131071
  int r = w >> 5;              // row 0..4095
  int u = w & 31;
  int isk = u >> 4, h = u & 15;
  float x = QKV[(size_t)r * 3072 + isk * 1024 + h * 64 + lane];
  float ss = x * x;
  #pragma unroll
  for (int off = 32; off >= 1; off >>= 1) ss += __shfl_xor(ss, off);
  float xn = x * rsqrtf(ss * (1.0f / 64.0f) + 1e-5f);
  int s = r & (SLEN - 1);
  int j = lane & 31;
  float c = cosT[s * 32 + j], sn = sinT[s * 32 + j];
  float other = __shfl_xor(xn, 32);
  // lane<32: x1*c + x2*s ; lane>=32: -x1*s + x2*c
  float o = (lane < 32) ? fmaf(xn, c, other * sn) : fmaf(xn, c, -other * sn);
  if (!isk) o *= q_gain[h];
  float* dst = isk ? KP : QP;
  dst[(size_t)r * 1024 + h * 64 + lane] = o;
}

// ---------------- fp32 one-pass flash attention (no max subtraction) --------
// Grid: (16 q-tiles of 128 rows, 32 hh, 2 b). Block = 256 = 4 waves.
// Lane owns q-rows (q0+lane, q0+64+lane); waves split K-chunks mod 4 and are
// fully independent in the K-loop (private 16KB LDS region, no barriers).
// Fixed softmax shift m=0: scores bounded (|s| <= ~11 from rmsnorm), so
// exp(s) and l fit fp32 comfortably; split-K partials combine additively.
__global__ void __launch_bounds__(256, 2) k_attn(const float* __restrict__ QP,
    const float* __restrict__ KP, const float* __restrict__ QKV,
    float* __restrict__ OH) {
  __shared__ float R[4][4096];      // per-wave: K[0..2047]=64x32, V[2048..4095]
  const int T = 15 - blockIdx.x;    // heavy tiles first
  const int hh = blockIdx.y, b = blockIdx.z;
  const int h = hh & 15, half = hh >> 4;
  const int q0 = T * 128;
  const int qkcol = h * 64 + half * 32;
  const int vcol = 2048 + qkcol;
  const int t = threadIdx.x;
  const int w = t >> 6, lane = t & 63;
  float* reg = R[w];

  const int row0 = q0 + lane, row1 = q0 + 64 + lane;
  // Q rows into registers (one-time, uncoalesced but tiny)
  float q0r[32], q1r[32];
  {
    const float* qp0 = QP + (size_t)(b * SLEN + row0) * 1024 + qkcol;
    const float* qp1 = QP + (size_t)(b * SLEN + row1) * 1024 + qkcol;
    #pragma unroll
    for (int j = 0; j < 8; ++j) {
      float4 a = *(const float4*)(qp0 + 4 * j);
      q0r[4 * j + 0] = a.x; q0r[4 * j + 1] = a.y; q0r[4 * j + 2] = a.z; q0r[4 * j + 3] = a.w;
      float4 c = *(const float4*)(qp1 + 4 * j);
      q1r[4 * j + 0] = c.x; q1r[4 * j + 1] = c.y; q1r[4 * j + 2] = c.z; q1r[4 * j + 3] = c.w;
    }
  }
  float acc0[32] = {}, acc1[32] = {};
  float l0 = 0.f, l1 = 0.f;
  const float sscale = 0.17677669529663687f;   // 1/sqrt(32)
  const int lastc = 2 * T + 1;
  const int lr = lane >> 3;          // staging: sub-row 0..7
  const int lc = (lane & 7) * 4;     // staging: float col 0,4,..28

  for (int cc = w; cc <= lastc; cc += 4) {
    const int k0 = cc * 64;
    // stage K,V chunk into private region: [kc][d] row-major, 32 floats/row
    {
      const float* kbase = KP  + (size_t)(b * SLEN + k0 + lr) * 1024 + qkcol + lc;
      const float* vbase = QKV + (size_t)(b * SLEN + k0 + lr) * 3072 + vcol  + lc;
      #pragma unroll
      for (int i = 0; i < 8; ++i) {
        float4 kk = *(const float4*)(kbase + (size_t)i * 8 * 1024);
        float4 vv = *(const float4*)(vbase + (size_t)i * 8 * 3072);
        *(float4*)(reg + i * 256 + lane * 4)        = kk;   // kc = i*8+lr
        *(float4*)(reg + 2048 + i * 256 + lane * 4) = vv;
      }
    }
    const int n0 = row0 - k0 + 1;    // #valid kc for row0 (<=0 none, >=64 all)
    const int n1 = row1 - k0 + 1;
    #pragma unroll 2
    for (int kc = 0; kc < 64; ++kc) {
      const float* kr = reg + kc * 32;
      float s0a = 0.f, s0b = 0.f, s1a = 0.f, s1b = 0.f;
      #pragma unroll
      for (int j = 0; j < 4; ++j) {
        float4 ka = *(const float4*)(kr + 8 * j);
        float4 kb = *(const float4*)(kr + 8 * j + 4);
        s0a = fmaf(q0r[8 * j + 0], ka.x, s0a);
        s0a = fmaf(q0r[8 * j + 1], ka.y, s0a);
        s0a = fmaf(q0r[8 * j + 2], ka.z, s0a);
        s0a = fmaf(q0r[8 * j + 3], ka.w, s0a);
        s0b = fmaf(q0r[8 * j + 4], kb.x, s0b);
        s0b = fmaf(q0r[8 * j + 5], kb.y, s0b);
        s0b = fmaf(q0r[8 * j + 6], kb.z, s0b);
        s0b = fmaf(q0r[8 * j + 7], kb.w, s0b);
        s1a = fmaf(q1r[8 * j + 0], ka.x, s1a);
        s1a = fmaf(q1r[8 * j + 1], ka.y, s1a);
        s1a = fmaf(q1r[8 * j + 2], ka.z, s1a);
        s1a = fmaf(q1r[8 * j + 3], ka.w, s1a);
        s1b = fmaf(q1r[8 * j + 4], kb.x, s1b);
        s1b = fmaf(q1r[8 * j + 5], kb.y, s1b);
        s1b = fmaf(q1r[8 * j + 6], kb.z, s1b);
        s1b = fmaf(q1r[8 * j + 7], kb.w, s1b);
      }
      float s0 = (s0a + s0b) * sscale;
      float s1 = (s1a + s1b) * sscale;
      float p0 = (kc < n0) ? __expf(s0) : 0.f;
      float p1 = (kc < n1) ? __expf(s1) : 0.f;
      l0 += p0; l1 += p1;
      const float* vr = reg + 2048 + kc * 32;
      #pragma unroll
      for (int j = 0; j < 8; ++j) {
        float4 vv = *(const float4*)(vr + 4 * j);
        acc0[4 * j + 0] = fmaf(p0, vv.x, acc0[4 * j + 0]);
        acc0[4 * j + 1] = fmaf(p0, vv.y, acc0[4 * j + 1]);
        acc0[4 * j + 2] = fmaf(p0, vv.z, acc0[4 * j + 2]);
        acc0[4 * j + 3] = fmaf(p0, vv.w, acc0[4 * j + 3]);
        acc1[4 * j + 0] = fmaf(p1, vv.x, acc1[4 * j + 0]);
        acc1[4 * j + 1] = fmaf(p1, vv.y, acc1[4 * j + 1]);
        acc1[4 * j + 2] = fmaf(p1, vv.z, acc1[4 * j + 2]);
        acc1[4 * j + 3] = fmaf(p1, vv.w, acc1[4 * j + 3]);
      }
    }
  }

  // ---- cross-wave combine: l first, then scaled acc ----
  reg[lane] = l0; reg[64 + lane] = l1;
  __syncthreads();
  float ls0 = R[0][lane] + R[1][lane] + R[2][lane] + R[3][lane];
  float ls1 = R[0][64 + lane] + R[1][64 + lane] + R[2][64 + lane] + R[3][64 + lane];
  float inv0 = 1.0f / ls0, inv1 = 1.0f / ls1;
  __syncthreads();
  #pragma unroll
  for (int j = 0; j < 8; ++j) {
    float4 o0 = {acc0[4 * j] * inv0, acc0[4 * j + 1] * inv0,
                 acc0[4 * j + 2] * inv0, acc0[4 * j + 3] * inv0};
    *(float4*)(reg + lane * 32 + 4 * j) = o0;
    float4 o1 = {acc1[4 * j] * inv1, acc1[4 * j + 1] * inv1,
                 acc1[4 * j + 2] * inv1, acc1[4 * j + 3] * inv1};
    *(float4*)(reg + (64 + lane) * 32 + 4 * j) = o1;
  }
  __syncthreads();
  {
    const int row = t >> 1, d0 = (t & 1) * 16;
    const size_t gr = (size_t)(b * SLEN + q0 + row) * 32 + hh;
    #pragma unroll
    for (int j = 0; j < 4; ++j) {
      int idx = row * 32 + d0 + 4 * j;
      float4 a = *(const float4*)&R[0][idx];
      float4 c = *(const float4*)&R[1][idx];
      float4 d = *(const float4*)&R[2][idx];
      float4 e = *(const float4*)&R[3][idx];
      float4 s = {a.x + c.x + d.x + e.x, a.y + c.y + d.y + e.y,
                  a.z + c.z + d.z + e.z, a.w + c.w + d.w + e.w};
      *(float4*)(OH + gr * 32 + d0 + 4 * j) = s;
    }
  }
}

// ---------------- differential combine: y = [y1 - lam*y2, y1 + lam*y2] -------
__global__ void __launch_bounds__(256) k_combine(const float* __restrict__ OH,
    const float* __restrict__ dl, float* __restrict__ Y) {
  int idx = blockIdx.x * 256 + threadIdx.x;   // 4096*16*32
  int d = idx & 31;
  int h = (idx >> 5) & 15;
  int r = idx >> 9;
  float y1 = OH[((size_t)r * 32 + h) * 32 + d];
  float y2 = OH[((size_t)r * 32 + h + 16) * 32 + d];
  float lam = dl[h];
  Y[(size_t)r * 1024 + h * 64 + d]      = y1 - lam * y2;
  Y[(size_t)r * 1024 + h * 64 + 32 + d] = y1 + lam * y2;
}

// ---------------- prototype projection -> A1T[f][o], A2T[f][o] ----------------
__global__ void __launch_bounds__(256) k_protproj(const float* __restrict__ PT,
    const float* __restrict__ features, const float* __restrict__ thp,
    const float* __restrict__ alp, const float* __restrict__ bep,
    float* __restrict__ A1T, float* __restrict__ A2T) {
  int o = blockIdx.x, t = threadIdx.x;
  int f = t >> 4, seg = t & 15;
  const float* pr = PT + (size_t)o * 1024 + seg * 64;
  const float* fr = features + (size_t)f * 1024 + seg * 64;
  float acc = 0.0f;
  #pragma unroll
  for (int i = 0; i < 64; i += 4) {
    float4 a = *(const float4*)(pr + i);
    float4 bq = *(const float4*)(fr + i);
    acc = fmaf(a.x, bq.x, acc); acc = fmaf(a.y, bq.y, acc);
    acc = fmaf(a.z, bq.z, acc); acc = fmaf(a.w, bq.w, acc);
  }
  acc += __shfl_xor(acc, 1); acc += __shfl_xor(acc, 2);
  acc += __shfl_xor(acc, 4); acc += __shfl_xor(acc, 8);
  if (seg == 0) {
    float pf = acc;
    float ps = 1.0f / (1.0f + expf(-5.0f * pf));
    float pa = pf * ps;
    A1T[f * 1024 + o] = fabsf(*thp) * pa - fabsf(*alp) * (1.0f - ps);
    A2T[f * 1024 + o] = -fabsf(*bep) * pa;
  }
}

// ---------------- x features: x_a and (1-x_s) ----------------
__global__ void __launch_bounds__(256) k_xfeat(const float* __restrict__ Y,
    const float* __restrict__ features, float* __restrict__ XA, float* __restrict__ XS1) {
  int r = blockIdx.x, t = threadIdx.x;
  int f = t >> 4, seg = t & 15;
  const float* yr = Y + (size_t)r * 1024 + seg * 64;
  const float* fr = features + (size_t)f * 1024 + seg * 64;
  float acc = 0.0f;
  #pragma unroll
  for (int i = 0; i < 64; i += 4) {
    float4 a = *(const float4*)(yr + i);
    float4 bq = *(const float4*)(fr + i);
    acc = fmaf(a.x, bq.x, acc); acc = fmaf(a.y, bq.y, acc);
    acc = fmaf(a.z, bq.z, acc); acc = fmaf(a.w, bq.w, acc);
  }
  acc += __shfl_xor(acc, 1); acc += __shfl_xor(acc, 2);
  acc += __shfl_xor(acc, 4); acc += __shfl_xor(acc, 8);
  if (seg == 0) {
    float xf = acc;
    float xs = 1.0f / (1.0f + expf(-5.0f * xf));
    XA[r * 16 + f] = xf * xs;
    XS1[r * 16 + f] = 1.0f - xs;
  }
}

// ---------------- final: out = XA @ A1T + XS1 @ A2T ----------------
__global__ void __launch_bounds__(256) k_final(const float* __restrict__ XA,
    const float* __restrict__ XS1, const float* __restrict__ A1T,
    const float* __restrict__ A2T, float* __restrict__ out) {
  int r = blockIdx.x, t = threadIdx.x;
  float xa[16], x1[16];
  #pragma unroll
  for (int f4 = 0; f4 < 16; f4 += 4) {
    float4 a = *(const float4*)(XA + r * 16 + f4);
    float4 b = *(const float4*)(XS1 + r * 16 + f4);
    xa[f4] = a.x; xa[f4 + 1] = a.y; xa[f4 + 2] = a.z; xa[f4 + 3] = a.w;
    x1[f4] = b.x; x1[f4 + 1] = b.y; x1[f4 + 2] = b.z; x1[f4 + 3] = b.w;
  }
  float4 acc = {0.f, 0.f, 0.f, 0.f};
  #pragma unroll
  for (int f = 0; f < 16; ++f) {
    float4 a1 = *(const float4*)(A1T + f * 1024 + t * 4);
    float4 a2 = *(const float4*)(A2T + f * 1024 + t * 4);
    acc.x = fmaf(xa[f], a1.x, fmaf(x1[f], a2.x, acc.x));
    acc.y = fmaf(xa[f], a1.y, fmaf(x1[f], a2.y, acc.y));
    acc.z = fmaf(xa[f], a1.z, fmaf(x1[f], a2.z, acc.z));
    acc.w = fmaf(xa[f], a1.w, fmaf(x1[f], a2.w, acc.w));
  }
  *(float4*)(out + (size_t)r * 1024 + t * 4) = acc;
}

extern "C" void kernel_launch(void* const* d_in, const int* in_sizes, int n_in,
                              void* d_out, int out_size, void* d_ws, size_t ws_size,
                              hipStream_t stream) {
  const float* x      = (const float*)d_in[0];
  const float* w_qkv  = (const float*)d_in[1];
  const float* feats  = (const float*)d_in[2];
  const float* protos = (const float*)d_in[3];
  const float* theta  = (const float*)d_in[4];
  const float* alpha  = (const float*)d_in[5];
  const float* beta   = (const float*)d_in[6];
  const float* q_gain = (const float*)d_in[7];
  const float* dlam   = (const float*)d_in[8];
  float* out = (float*)d_out;
  float* ws  = (float*)d_ws;

  // workspace layout (floats)
  float* W_T = ws;                    // 3,145,728
  float* QKV = W_T + 3145728;         // 12,582,912
  float* QP  = QKV + 12582912;        // 4,194,304
  float* KP  = QP  + 4194304;         // 4,194,304
  float* OH  = KP  + 4194304;         // 4,194,304
  float* Y   = OH  + 4194304;         // 4,194,304
  float* COS = Y   + 4194304;         // 65,536
  float* SIN = COS + 65536;           // 65,536
  float* PT  = SIN + 65536;           // 1,048,576
  float* A1T = PT  + 1048576;         // 16,384
  float* A2T = A1T + 16384;           // 16,384
  float* XA  = A2T + 16384;           // 65,536
  float* XS1 = XA  + 65536;           // 65,536

  k_rope_tab<<<256, 256, 0, stream>>>(COS, SIN);
  k_ternary<<<12288, 256, 0, stream>>>(w_qkv, W_T);     // 3,145,728 elems
  k_ternary<<<4096, 256, 0, stream>>>(protos, PT);      // 1,048,576 elems
  dim3 gg(QKV_N / 128, NROWS / 128);
  k_gemm_nt<<<gg, 256, 0, stream>>>(x, W_T, QKV, NROWS, QKV_N, DIM);
  k_normrope<<<32768, 256, 0, stream>>>(QKV, COS, SIN, q_gain, QP, KP);
  dim3 ga(16, 32, BATCH);
  k_attn<<<ga, 256, 0, stream>>>(QP, KP, QKV, OH);
  k_combine<<<8192, 256, 0, stream>>>(OH, dlam, Y);
  k_protproj<<<1024, 256, 0, stream>>>(PT, feats, theta, alpha, beta, A1T, A2T);
  k_xfeat<<<4096, 256, 0, stream>>>(Y, feats, XA, XS1);
  k_final<<<4096, 256, 0, stream>>>(XA, XS1, A1T, A2T, out);
}